// Round 4
// baseline (302.209 us; speedup 1.0000x reference)
//
#include <hip/hip_runtime.h>
#include <hip/hip_bf16.h>
#include <math.h>

#define LN_EPS 1e-5f

typedef short bf16x8 __attribute__((ext_vector_type(8)));
typedef float f32x4 __attribute__((ext_vector_type(4)));

__device__ inline short f2bf(float f) {
  union { float f; unsigned u; } v; v.f = f;
  unsigned r = v.u + 0x7FFFu + ((v.u >> 16) & 1u);
  return (short)(r >> 16);
}
__device__ inline float bf2f(unsigned short s) {
  union { unsigned u; float f; } v; v.u = ((unsigned)s) << 16;
  return v.f;
}
__device__ inline float fast_exp2(float x) {
#if __has_builtin(__builtin_amdgcn_exp2f)
  return __builtin_amdgcn_exp2f(x);
#else
  return __expf(x * 0.69314718056f);
#endif
}

// ---------------- GEMM: featproj(bf16) = A_f32(M x 256) @ Wf(256 x 256)^T + bf --
__global__ __launch_bounds__(256) void gemm_feat(const float* __restrict__ Ap,
    const float* __restrict__ W, const float* __restrict__ bias,
    short* __restrict__ Out)
{
  __shared__ short lda[64][40];
  __shared__ short ldb[64][40];
  const int tid = threadIdx.x;
  const int bm = blockIdx.x * 64, bn = blockIdx.y * 64;
  const int wid = tid >> 6, lane = tid & 63;
  const int quad = lane >> 4, l15 = lane & 15;
  const int wm = (wid & 1) * 32, wn = (wid >> 1) * 32;
  const int srow = tid >> 2, sseg = tid & 3;

  f32x4 z = {0.f, 0.f, 0.f, 0.f};
  f32x4 acc[2][2];
  acc[0][0] = z; acc[0][1] = z; acc[1][0] = z; acc[1][1] = z;

  for (int kk = 0; kk < 256; kk += 32) {
    {
      const float* ap = Ap + (size_t)(bm + srow) * 256 + kk + sseg * 8;
      f32x4 x0 = *(const f32x4*)ap;
      f32x4 x1 = *(const f32x4*)(ap + 4);
      bf16x8 vv;
      vv[0] = f2bf(x0[0]); vv[1] = f2bf(x0[1]); vv[2] = f2bf(x0[2]); vv[3] = f2bf(x0[3]);
      vv[4] = f2bf(x1[0]); vv[5] = f2bf(x1[1]); vv[6] = f2bf(x1[2]); vv[7] = f2bf(x1[3]);
      *(bf16x8*)&lda[srow][sseg * 8] = vv;
    }
    {
      const float* wp = W + (size_t)(bn + srow) * 256 + kk + sseg * 8;
      f32x4 x0 = *(const f32x4*)wp;
      f32x4 x1 = *(const f32x4*)(wp + 4);
      bf16x8 vv;
      vv[0] = f2bf(x0[0]); vv[1] = f2bf(x0[1]); vv[2] = f2bf(x0[2]); vv[3] = f2bf(x0[3]);
      vv[4] = f2bf(x1[0]); vv[5] = f2bf(x1[1]); vv[6] = f2bf(x1[2]); vv[7] = f2bf(x1[3]);
      *(bf16x8*)&ldb[srow][sseg * 8] = vv;
    }
    __syncthreads();
    bf16x8 af0 = *(const bf16x8*)&lda[wm + l15][quad * 8];
    bf16x8 af1 = *(const bf16x8*)&lda[wm + 16 + l15][quad * 8];
    bf16x8 bq0 = *(const bf16x8*)&ldb[wn + l15][quad * 8];
    bf16x8 bq1 = *(const bf16x8*)&ldb[wn + 16 + l15][quad * 8];
    acc[0][0] = __builtin_amdgcn_mfma_f32_16x16x32_bf16(af0, bq0, acc[0][0], 0, 0, 0);
    acc[0][1] = __builtin_amdgcn_mfma_f32_16x16x32_bf16(af0, bq1, acc[0][1], 0, 0, 0);
    acc[1][0] = __builtin_amdgcn_mfma_f32_16x16x32_bf16(af1, bq0, acc[1][0], 0, 0, 0);
    acc[1][1] = __builtin_amdgcn_mfma_f32_16x16x32_bf16(af1, bq1, acc[1][1], 0, 0, 0);
    __syncthreads();
  }

  #pragma unroll
  for (int i = 0; i < 2; ++i)
    #pragma unroll
    for (int j = 0; j < 2; ++j)
      #pragma unroll
      for (int r = 0; r < 4; ++r) {
        int grow = bm + wm + i * 16 + quad * 4 + r;
        int gcol = bn + wn + j * 16 + l15;
        Out[(size_t)grow * 256 + gcol] = f2bf(acc[i][j][r] + bias[gcol]);
      }
}

// Q/K projection fused: z=0 -> q from tok_cur (scale * log2e folded), z=1 -> k
__global__ __launch_bounds__(256) void gemm_qk(const short* __restrict__ tokc,
    const short* __restrict__ tokp, const float* __restrict__ Win,
    const float* __restrict__ binv, short* __restrict__ qb, short* __restrict__ kb)
{
  const int sel = blockIdx.z;
  const short* Ap = sel ? tokp : tokc;
  const float* W = Win + (size_t)sel * 65536;
  const float* bias = binv + sel * 256;
  const float alpha = sel ? 1.0f : 0.17677669529663687f * 1.4426950408889634f;
  short* Out = sel ? kb : qb;

  __shared__ short lda[64][40];
  __shared__ short ldb[64][40];
  const int tid = threadIdx.x;
  const int bm = blockIdx.x * 64, bn = blockIdx.y * 64;
  const int wid = tid >> 6, lane = tid & 63;
  const int quad = lane >> 4, l15 = lane & 15;
  const int wm = (wid & 1) * 32, wn = (wid >> 1) * 32;
  const int srow = tid >> 2, sseg = tid & 3;

  f32x4 z = {0.f, 0.f, 0.f, 0.f};
  f32x4 acc[2][2];
  acc[0][0] = z; acc[0][1] = z; acc[1][0] = z; acc[1][1] = z;

  for (int kk = 0; kk < 256; kk += 32) {
    *(bf16x8*)&lda[srow][sseg * 8] =
        *(const bf16x8*)(Ap + (size_t)(bm + srow) * 256 + kk + sseg * 8);
    {
      const float* wp = W + (size_t)(bn + srow) * 256 + kk + sseg * 8;
      f32x4 x0 = *(const f32x4*)wp;
      f32x4 x1 = *(const f32x4*)(wp + 4);
      bf16x8 vv;
      vv[0] = f2bf(x0[0]); vv[1] = f2bf(x0[1]); vv[2] = f2bf(x0[2]); vv[3] = f2bf(x0[3]);
      vv[4] = f2bf(x1[0]); vv[5] = f2bf(x1[1]); vv[6] = f2bf(x1[2]); vv[7] = f2bf(x1[3]);
      *(bf16x8*)&ldb[srow][sseg * 8] = vv;
    }
    __syncthreads();
    bf16x8 af0 = *(const bf16x8*)&lda[wm + l15][quad * 8];
    bf16x8 af1 = *(const bf16x8*)&lda[wm + 16 + l15][quad * 8];
    bf16x8 bq0 = *(const bf16x8*)&ldb[wn + l15][quad * 8];
    bf16x8 bq1 = *(const bf16x8*)&ldb[wn + 16 + l15][quad * 8];
    acc[0][0] = __builtin_amdgcn_mfma_f32_16x16x32_bf16(af0, bq0, acc[0][0], 0, 0, 0);
    acc[0][1] = __builtin_amdgcn_mfma_f32_16x16x32_bf16(af0, bq1, acc[0][1], 0, 0, 0);
    acc[1][0] = __builtin_amdgcn_mfma_f32_16x16x32_bf16(af1, bq0, acc[1][0], 0, 0, 0);
    acc[1][1] = __builtin_amdgcn_mfma_f32_16x16x32_bf16(af1, bq1, acc[1][1], 0, 0, 0);
    __syncthreads();
  }

  #pragma unroll
  for (int i = 0; i < 2; ++i)
    #pragma unroll
    for (int j = 0; j < 2; ++j)
      #pragma unroll
      for (int r = 0; r < 4; ++r) {
        int grow = bm + wm + i * 16 + quad * 4 + r;
        int gcol = bn + wn + j * 16 + l15;
        float v = (acc[i][j][r] + bias[gcol]) * alpha;
        int btr = grow >> 10, nn = grow & 1023, h = gcol >> 5, d = gcol & 31;
        Out[(((size_t)btr * 8 + h) * 1024 + nn) * 32 + d] = f2bf(v);
      }
}

// ---- anchor transform + A-proj + LayerNorm, wave-per-token ---------------------
__global__ __launch_bounds__(256) void anchor_ln(const short* __restrict__ featproj,
  const float* __restrict__ anchors, const float* __restrict__ Tego,
  const float* __restrict__ Wa, const float* __restrict__ ba,
  const float* __restrict__ gamma, const float* __restrict__ beta,
  short* __restrict__ tok_cur, short* __restrict__ tok_prev)
{
  const int wid = threadIdx.x >> 6, lane = threadIdx.x & 63;
  const int tok = blockIdx.x * 4 + wid;
  const int which = tok >= 22528 ? 1 : 0;
  const int rem = tok - which * 22528;
  const int bt = rem >> 10;
  const int n = rem & 1023;
  const int b = bt / 11, t = bt - b * 11;
  const int tt = which ? t : t + 1;

  const float* ap = anchors + (((size_t)b * 12 + tt) * 1024 + n) * 11;
  float a[11];
  #pragma unroll
  for (int j = 0; j < 11; ++j) a[j] = ap[j];
  if (which) {
    const float* Tm = Tego + ((size_t)b * 12 + t + 1) * 16;
    float r00 = Tm[0], r01 = Tm[1], r02 = Tm[2],  t0 = Tm[3];
    float r10 = Tm[4], r11 = Tm[5], r12 = Tm[6],  t1 = Tm[7];
    float r20 = Tm[8], r21 = Tm[9], r22 = Tm[10], t2 = Tm[11];
    float a0 = a[0], a1 = a[1], a2 = a[2];
    float a6 = a[6], a7 = a[7], a8 = a[8], a9 = a[9], a10 = a[10];
    a[0] = r00 * a0 + r01 * a1 + r02 * a2 + t0;
    a[1] = r10 * a0 + r11 * a1 + r12 * a2 + t1;
    a[2] = r20 * a0 + r21 * a1 + r22 * a2 + t2;
    a[6] = r00 * a6 + r01 * a7;
    a[7] = r10 * a6 + r11 * a7;
    a[8] = r00 * a8 + r01 * a9 + r02 * a10;
    a[9] = r10 * a8 + r11 * a9 + r12 * a10;
    a[10] = r20 * a8 + r21 * a9 + r22 * a10;
  }

  const int c0 = lane * 4;
  const size_t frow = (((size_t)b * 12 + tt) * 1024 + n) * 256 + c0;
  ushort4 raw = *(const ushort4*)(featproj + frow);
  f32x4 bav = *(const f32x4*)(ba + c0);
  float v[4];
  v[0] = bf2f(raw.x) + bav[0]; v[1] = bf2f(raw.y) + bav[1];
  v[2] = bf2f(raw.z) + bav[2]; v[3] = bf2f(raw.w) + bav[3];
  #pragma unroll
  for (int c = 0; c < 4; ++c) {
    const float* war = Wa + (size_t)(c0 + c) * 11;
    float acc = 0.f;
    #pragma unroll
    for (int j = 0; j < 11; ++j) acc += war[j] * a[j];
    v[c] += acc;
  }
  float s1 = v[0] + v[1] + v[2] + v[3];
  float s2 = v[0]*v[0] + v[1]*v[1] + v[2]*v[2] + v[3]*v[3];
  #pragma unroll
  for (int off = 1; off < 64; off <<= 1) { s1 += __shfl_xor(s1, off); s2 += __shfl_xor(s2, off); }
  float mean = s1 * (1.0f / 256.0f);
  float var = s2 * (1.0f / 256.0f) - mean * mean;
  float rstd = rsqrtf(var + LN_EPS);
  f32x4 gv = *(const f32x4*)(gamma + c0);
  f32x4 bv = *(const f32x4*)(beta + c0);
  ushort4 o;
  o.x = (unsigned short)f2bf((v[0] - mean) * rstd * gv[0] + bv[0]);
  o.y = (unsigned short)f2bf((v[1] - mean) * rstd * gv[1] + bv[1]);
  o.z = (unsigned short)f2bf((v[2] - mean) * rstd * gv[2] + bv[2]);
  o.w = (unsigned short)f2bf((v[3] - mean) * rstd * gv[3] + bv[3]);
  short* dst = which ? tok_prev : tok_cur;
  *(ushort4*)(dst + ((size_t)bt * 1024 + n) * 256 + c0) = o;
}

// -------- pass 1: denominators; ping-pong prefetch of 4-row k groups -----------
__global__ __launch_bounds__(256) void denom_kernel(const short* __restrict__ q,
  const short* __restrict__ k, float* __restrict__ dinv)
{
  const int tid = threadIdx.x, wid = tid >> 6, lane = tid & 63;
  const int quad = lane >> 4, l15 = lane & 15;
  const int h = blockIdx.y, bt = blockIdx.z;
  const int n0 = blockIdx.x * 64 + wid * 16;
  const size_t base = ((size_t)bt * 8 + h) * 1024 * 32;
  bf16x8 qf = *(const bf16x8*)(q + base + (size_t)(n0 + l15) * 32 + quad * 8);
  const short* kbp = k + base + (size_t)l15 * 32 + quad * 8;
  f32x4 z = {0.f, 0.f, 0.f, 0.f};
  float sum0 = 0, sum1 = 0, sum2 = 0, sum3 = 0;

  bf16x8 ka[4], kbuf[4];
  #pragma unroll
  for (int i = 0; i < 4; ++i) ka[i] = *(const bf16x8*)(kbp + (size_t)(i * 16) * 32);

  #pragma unroll 1
  for (int m0 = 0; m0 < 1024; m0 += 128) {
    #pragma unroll
    for (int i = 0; i < 4; ++i)
      kbuf[i] = *(const bf16x8*)(kbp + (size_t)(m0 + 64 + i * 16) * 32);
    #pragma unroll
    for (int i = 0; i < 4; ++i) {
      f32x4 s = __builtin_amdgcn_mfma_f32_16x16x32_bf16(qf, ka[i], z, 0, 0, 0);
      sum0 += fast_exp2(s[0]); sum1 += fast_exp2(s[1]);
      sum2 += fast_exp2(s[2]); sum3 += fast_exp2(s[3]);
    }
    int mn = (m0 + 128) < 1024 ? (m0 + 128) : 0;
    #pragma unroll
    for (int i = 0; i < 4; ++i)
      ka[i] = *(const bf16x8*)(kbp + (size_t)(mn + i * 16) * 32);
    #pragma unroll
    for (int i = 0; i < 4; ++i) {
      f32x4 s = __builtin_amdgcn_mfma_f32_16x16x32_bf16(qf, kbuf[i], z, 0, 0, 0);
      sum0 += fast_exp2(s[0]); sum1 += fast_exp2(s[1]);
      sum2 += fast_exp2(s[2]); sum3 += fast_exp2(s[3]);
    }
  }
  #pragma unroll
  for (int off = 1; off < 16; off <<= 1) {
    sum0 += __shfl_xor(sum0, off); sum1 += __shfl_xor(sum1, off);
    sum2 += __shfl_xor(sum2, off); sum3 += __shfl_xor(sum3, off);
  }
  if (l15 == 0) {
    float* dp = dinv + ((size_t)bt * 8 + h) * 1024 + n0 + quad * 4;
    dp[0] = 1.f / sum0; dp[1] = 1.f / sum1; dp[2] = 1.f / sum2; dp[3] = 1.f / sum3;
  }
}

// -------- pass 2: probabilities; ping-pong prefetch of 8-head k groups ---------
__global__ __launch_bounds__(256) void prob_kernel(const short* __restrict__ q,
  const short* __restrict__ k, const float* __restrict__ dinv, float* __restrict__ out)
{
  const int tid = threadIdx.x, wid = tid >> 6, lane = tid & 63;
  const int quad = lane >> 4, l15 = lane & 15;
  const int bt = blockIdx.z;
  const int n0 = blockIdx.x * 64 + wid * 16;
  const int mbase = blockIdx.y * 128;
  const int b = bt / 11, t = bt - b * 11;
  bf16x8 qf[8];
  float invd[8][4];
  #pragma unroll
  for (int h = 0; h < 8; ++h) {
    const size_t base = ((size_t)bt * 8 + h) * 1024 * 32;
    qf[h] = *(const bf16x8*)(q + base + (size_t)(n0 + l15) * 32 + quad * 8);
    const float* dp = dinv + ((size_t)bt * 8 + h) * 1024 + n0 + quad * 4;
    #pragma unroll
    for (int r = 0; r < 4; ++r) invd[h][r] = dp[r] * 0.125f;
  }
  const short* kbp = k + ((size_t)bt * 8) * 1024 * 32 + (size_t)l15 * 32 + quad * 8;
  float* ob = out + ((size_t)(b * 12 + t + 1)) * 1024 * 1024
                  + (size_t)(n0 + quad * 4) * 1024 + l15;
  f32x4 z = {0.f, 0.f, 0.f, 0.f};

  bf16x8 ka[8], kbb[8];
  #pragma unroll
  for (int h = 0; h < 8; ++h)
    ka[h] = *(const bf16x8*)(kbp + ((size_t)h * 1024 + mbase) * 32);

  #pragma unroll 1
  for (int m0 = mbase; m0 < mbase + 128; m0 += 32) {
    #pragma unroll
    for (int h = 0; h < 8; ++h)
      kbb[h] = *(const bf16x8*)(kbp + ((size_t)h * 1024 + m0 + 16) * 32);
    {
      float P0 = 0, P1 = 0, P2 = 0, P3 = 0;
      #pragma unroll
      for (int h = 0; h < 8; ++h) {
        f32x4 s = __builtin_amdgcn_mfma_f32_16x16x32_bf16(qf[h], ka[h], z, 0, 0, 0);
        P0 += fast_exp2(s[0]) * invd[h][0];
        P1 += fast_exp2(s[1]) * invd[h][1];
        P2 += fast_exp2(s[2]) * invd[h][2];
        P3 += fast_exp2(s[3]) * invd[h][3];
      }
      float* op = ob + (m0 - 0);
      op[0] = P0; op[1024] = P1; op[2048] = P2; op[3072] = P3;
    }
    int mn = (m0 + 32) < mbase + 128 ? (m0 + 32) : mbase;
    #pragma unroll
    for (int h = 0; h < 8; ++h)
      ka[h] = *(const bf16x8*)(kbp + ((size_t)h * 1024 + mn) * 32);
    {
      float P0 = 0, P1 = 0, P2 = 0, P3 = 0;
      #pragma unroll
      for (int h = 0; h < 8; ++h) {
        f32x4 s = __builtin_amdgcn_mfma_f32_16x16x32_bf16(qf[h], kbb[h], z, 0, 0, 0);
        P0 += fast_exp2(s[0]) * invd[h][0];
        P1 += fast_exp2(s[1]) * invd[h][1];
        P2 += fast_exp2(s[2]) * invd[h][2];
        P3 += fast_exp2(s[3]) * invd[h][3];
      }
      float* op = ob + (m0 + 16);
      op[0] = P0; op[1024] = P1; op[2048] = P2; op[3072] = P3;
    }
  }
}

// -------------- identity slab at t=0 -------------------------------------------
__global__ __launch_bounds__(256) void eye_kernel(float* __restrict__ out) {
  int gid = blockIdx.x * 256 + threadIdx.x;
  int b = gid >> 18, rem = gid & 262143;
  int n = rem >> 8, m4 = rem & 255;
  f32x4 v = {0.f, 0.f, 0.f, 0.f};
  int c = n - m4 * 4;
  if (c >= 0 && c < 4) v[c] = 1.0f;
  *(f32x4*)(out + (size_t)b * 12582912 + (size_t)n * 1024 + m4 * 4) = v;
}

extern "C" void kernel_launch(void* const* d_in, const int* in_sizes, int n_in,
                              void* d_out, int out_size, void* d_ws, size_t ws_size,
                              hipStream_t stream)
{
  const float* sf   = (const float*)d_in[0];
  const float* sa   = (const float*)d_in[1];
  const float* te   = (const float*)d_in[2];
  const float* Wf   = (const float*)d_in[3];
  const float* bfv  = (const float*)d_in[4];
  const float* Wa   = (const float*)d_in[5];
  const float* ba   = (const float*)d_in[6];
  const float* Win  = (const float*)d_in[7];
  const float* binv = (const float*)d_in[8];
  const float* gam  = (const float*)d_in[9];
  const float* bet  = (const float*)d_in[10];
  float* out = (float*)d_out;

  char* w = (char*)d_ws;
  short* featproj = (short*)w;  w += 12582912;
  short* tok_cur  = (short*)w;  w += 11534336;
  short* tok_prev = (short*)w;  w += 11534336;
  short* qb       = (short*)w;  w += 11534336;
  short* kb       = (short*)w;  w += 11534336;
  float* dinv     = (float*)w;  w += 720896;

  gemm_feat<<<dim3(384, 4), 256, 0, stream>>>(sf, Wf, bfv, featproj);
  anchor_ln<<<dim3(11264), 256, 0, stream>>>(featproj, sa, te, Wa, ba, gam, bet, tok_cur, tok_prev);
  gemm_qk<<<dim3(352, 4, 2), 256, 0, stream>>>(tok_cur, tok_prev, Win, binv, qb, kb);
  denom_kernel<<<dim3(16, 8, 22), 256, 0, stream>>>(qb, kb, dinv);
  prob_kernel<<<dim3(16, 8, 22), 256, 0, stream>>>(qb, kb, dinv, out);
  eye_kernel<<<dim3(2048), 256, 0, stream>>>(out);
}

// Round 5
// 271.591 us; speedup vs baseline: 1.1127x; 1.1127x over previous
//
#include <hip/hip_runtime.h>
#include <hip/hip_bf16.h>
#include <math.h>

#define LN_EPS 1e-5f

typedef short bf16x8 __attribute__((ext_vector_type(8)));
typedef float f32x4 __attribute__((ext_vector_type(4)));

__device__ inline short f2bf(float f) {
  union { float f; unsigned u; } v; v.f = f;
  unsigned r = v.u + 0x7FFFu + ((v.u >> 16) & 1u);
  return (short)(r >> 16);
}
__device__ inline float bf2f(unsigned short s) {
  union { unsigned u; float f; } v; v.u = ((unsigned)s) << 16;
  return v.f;
}
__device__ inline float fast_exp2(float x) {
#if __has_builtin(__builtin_amdgcn_exp2f)
  return __builtin_amdgcn_exp2f(x);
#else
  return __expf(x * 0.69314718056f);
#endif
}

// ---------------- GEMM: featproj(bf16) = A_f32(M x 256) @ Wf(256 x 256)^T + bf --
__global__ __launch_bounds__(256) void gemm_feat(const float* __restrict__ Ap,
    const float* __restrict__ W, const float* __restrict__ bias,
    short* __restrict__ Out)
{
  __shared__ short lda[64][40];
  __shared__ short ldb[64][40];
  const int tid = threadIdx.x;
  const int bm = blockIdx.x * 64, bn = blockIdx.y * 64;
  const int wid = tid >> 6, lane = tid & 63;
  const int quad = lane >> 4, l15 = lane & 15;
  const int wm = (wid & 1) * 32, wn = (wid >> 1) * 32;
  const int srow = tid >> 2, sseg = tid & 3;

  f32x4 z = {0.f, 0.f, 0.f, 0.f};
  f32x4 acc[2][2];
  acc[0][0] = z; acc[0][1] = z; acc[1][0] = z; acc[1][1] = z;

  for (int kk = 0; kk < 256; kk += 32) {
    {
      const float* ap = Ap + (size_t)(bm + srow) * 256 + kk + sseg * 8;
      f32x4 x0 = *(const f32x4*)ap;
      f32x4 x1 = *(const f32x4*)(ap + 4);
      bf16x8 vv;
      vv[0] = f2bf(x0[0]); vv[1] = f2bf(x0[1]); vv[2] = f2bf(x0[2]); vv[3] = f2bf(x0[3]);
      vv[4] = f2bf(x1[0]); vv[5] = f2bf(x1[1]); vv[6] = f2bf(x1[2]); vv[7] = f2bf(x1[3]);
      *(bf16x8*)&lda[srow][sseg * 8] = vv;
    }
    {
      const float* wp = W + (size_t)(bn + srow) * 256 + kk + sseg * 8;
      f32x4 x0 = *(const f32x4*)wp;
      f32x4 x1 = *(const f32x4*)(wp + 4);
      bf16x8 vv;
      vv[0] = f2bf(x0[0]); vv[1] = f2bf(x0[1]); vv[2] = f2bf(x0[2]); vv[3] = f2bf(x0[3]);
      vv[4] = f2bf(x1[0]); vv[5] = f2bf(x1[1]); vv[6] = f2bf(x1[2]); vv[7] = f2bf(x1[3]);
      *(bf16x8*)&ldb[srow][sseg * 8] = vv;
    }
    __syncthreads();
    bf16x8 af0 = *(const bf16x8*)&lda[wm + l15][quad * 8];
    bf16x8 af1 = *(const bf16x8*)&lda[wm + 16 + l15][quad * 8];
    bf16x8 bq0 = *(const bf16x8*)&ldb[wn + l15][quad * 8];
    bf16x8 bq1 = *(const bf16x8*)&ldb[wn + 16 + l15][quad * 8];
    acc[0][0] = __builtin_amdgcn_mfma_f32_16x16x32_bf16(af0, bq0, acc[0][0], 0, 0, 0);
    acc[0][1] = __builtin_amdgcn_mfma_f32_16x16x32_bf16(af0, bq1, acc[0][1], 0, 0, 0);
    acc[1][0] = __builtin_amdgcn_mfma_f32_16x16x32_bf16(af1, bq0, acc[1][0], 0, 0, 0);
    acc[1][1] = __builtin_amdgcn_mfma_f32_16x16x32_bf16(af1, bq1, acc[1][1], 0, 0, 0);
    __syncthreads();
  }

  #pragma unroll
  for (int i = 0; i < 2; ++i)
    #pragma unroll
    for (int j = 0; j < 2; ++j)
      #pragma unroll
      for (int r = 0; r < 4; ++r) {
        int grow = bm + wm + i * 16 + quad * 4 + r;
        int gcol = bn + wn + j * 16 + l15;
        Out[(size_t)grow * 256 + gcol] = f2bf(acc[i][j][r] + bias[gcol]);
      }
}

// Q/K projection fused: z=0 -> q from tok_cur (scale * log2e folded), z=1 -> k
__global__ __launch_bounds__(256) void gemm_qk(const short* __restrict__ tokc,
    const short* __restrict__ tokp, const float* __restrict__ Win,
    const float* __restrict__ binv, short* __restrict__ qb, short* __restrict__ kb)
{
  const int sel = blockIdx.z;
  const short* Ap = sel ? tokp : tokc;
  const float* W = Win + (size_t)sel * 65536;
  const float* bias = binv + sel * 256;
  const float alpha = sel ? 1.0f : 0.17677669529663687f * 1.4426950408889634f;
  short* Out = sel ? kb : qb;

  __shared__ short lda[64][40];
  __shared__ short ldb[64][40];
  const int tid = threadIdx.x;
  const int bm = blockIdx.x * 64, bn = blockIdx.y * 64;
  const int wid = tid >> 6, lane = tid & 63;
  const int quad = lane >> 4, l15 = lane & 15;
  const int wm = (wid & 1) * 32, wn = (wid >> 1) * 32;
  const int srow = tid >> 2, sseg = tid & 3;

  f32x4 z = {0.f, 0.f, 0.f, 0.f};
  f32x4 acc[2][2];
  acc[0][0] = z; acc[0][1] = z; acc[1][0] = z; acc[1][1] = z;

  for (int kk = 0; kk < 256; kk += 32) {
    *(bf16x8*)&lda[srow][sseg * 8] =
        *(const bf16x8*)(Ap + (size_t)(bm + srow) * 256 + kk + sseg * 8);
    {
      const float* wp = W + (size_t)(bn + srow) * 256 + kk + sseg * 8;
      f32x4 x0 = *(const f32x4*)wp;
      f32x4 x1 = *(const f32x4*)(wp + 4);
      bf16x8 vv;
      vv[0] = f2bf(x0[0]); vv[1] = f2bf(x0[1]); vv[2] = f2bf(x0[2]); vv[3] = f2bf(x0[3]);
      vv[4] = f2bf(x1[0]); vv[5] = f2bf(x1[1]); vv[6] = f2bf(x1[2]); vv[7] = f2bf(x1[3]);
      *(bf16x8*)&ldb[srow][sseg * 8] = vv;
    }
    __syncthreads();
    bf16x8 af0 = *(const bf16x8*)&lda[wm + l15][quad * 8];
    bf16x8 af1 = *(const bf16x8*)&lda[wm + 16 + l15][quad * 8];
    bf16x8 bq0 = *(const bf16x8*)&ldb[wn + l15][quad * 8];
    bf16x8 bq1 = *(const bf16x8*)&ldb[wn + 16 + l15][quad * 8];
    acc[0][0] = __builtin_amdgcn_mfma_f32_16x16x32_bf16(af0, bq0, acc[0][0], 0, 0, 0);
    acc[0][1] = __builtin_amdgcn_mfma_f32_16x16x32_bf16(af0, bq1, acc[0][1], 0, 0, 0);
    acc[1][0] = __builtin_amdgcn_mfma_f32_16x16x32_bf16(af1, bq0, acc[1][0], 0, 0, 0);
    acc[1][1] = __builtin_amdgcn_mfma_f32_16x16x32_bf16(af1, bq1, acc[1][1], 0, 0, 0);
    __syncthreads();
  }

  #pragma unroll
  for (int i = 0; i < 2; ++i)
    #pragma unroll
    for (int j = 0; j < 2; ++j)
      #pragma unroll
      for (int r = 0; r < 4; ++r) {
        int grow = bm + wm + i * 16 + quad * 4 + r;
        int gcol = bn + wn + j * 16 + l15;
        float v = (acc[i][j][r] + bias[gcol]) * alpha;
        int btr = grow >> 10, nn = grow & 1023, h = gcol >> 5, d = gcol & 31;
        Out[(((size_t)btr * 8 + h) * 1024 + nn) * 32 + d] = f2bf(v);
      }
}

// ---- anchor transform + A-proj + LayerNorm, wave-per-token ---------------------
__global__ __launch_bounds__(256) void anchor_ln(const short* __restrict__ featproj,
  const float* __restrict__ anchors, const float* __restrict__ Tego,
  const float* __restrict__ Wa, const float* __restrict__ ba,
  const float* __restrict__ gamma, const float* __restrict__ beta,
  short* __restrict__ tok_cur, short* __restrict__ tok_prev)
{
  const int wid = threadIdx.x >> 6, lane = threadIdx.x & 63;
  const int tok = blockIdx.x * 4 + wid;
  const int which = tok >= 22528 ? 1 : 0;
  const int rem = tok - which * 22528;
  const int bt = rem >> 10;
  const int n = rem & 1023;
  const int b = bt / 11, t = bt - b * 11;
  const int tt = which ? t : t + 1;

  const float* ap = anchors + (((size_t)b * 12 + tt) * 1024 + n) * 11;
  float a[11];
  #pragma unroll
  for (int j = 0; j < 11; ++j) a[j] = ap[j];
  if (which) {
    const float* Tm = Tego + ((size_t)b * 12 + t + 1) * 16;
    float r00 = Tm[0], r01 = Tm[1], r02 = Tm[2],  t0 = Tm[3];
    float r10 = Tm[4], r11 = Tm[5], r12 = Tm[6],  t1 = Tm[7];
    float r20 = Tm[8], r21 = Tm[9], r22 = Tm[10], t2 = Tm[11];
    float a0 = a[0], a1 = a[1], a2 = a[2];
    float a6 = a[6], a7 = a[7], a8 = a[8], a9 = a[9], a10 = a[10];
    a[0] = r00 * a0 + r01 * a1 + r02 * a2 + t0;
    a[1] = r10 * a0 + r11 * a1 + r12 * a2 + t1;
    a[2] = r20 * a0 + r21 * a1 + r22 * a2 + t2;
    a[6] = r00 * a6 + r01 * a7;
    a[7] = r10 * a6 + r11 * a7;
    a[8] = r00 * a8 + r01 * a9 + r02 * a10;
    a[9] = r10 * a8 + r11 * a9 + r12 * a10;
    a[10] = r20 * a8 + r21 * a9 + r22 * a10;
  }

  const int c0 = lane * 4;
  const size_t frow = (((size_t)b * 12 + tt) * 1024 + n) * 256 + c0;
  ushort4 raw = *(const ushort4*)(featproj + frow);
  f32x4 bav = *(const f32x4*)(ba + c0);
  float v[4];
  v[0] = bf2f(raw.x) + bav[0]; v[1] = bf2f(raw.y) + bav[1];
  v[2] = bf2f(raw.z) + bav[2]; v[3] = bf2f(raw.w) + bav[3];
  #pragma unroll
  for (int c = 0; c < 4; ++c) {
    const float* war = Wa + (size_t)(c0 + c) * 11;
    float acc = 0.f;
    #pragma unroll
    for (int j = 0; j < 11; ++j) acc += war[j] * a[j];
    v[c] += acc;
  }
  float s1 = v[0] + v[1] + v[2] + v[3];
  float s2 = v[0]*v[0] + v[1]*v[1] + v[2]*v[2] + v[3]*v[3];
  #pragma unroll
  for (int off = 1; off < 64; off <<= 1) { s1 += __shfl_xor(s1, off); s2 += __shfl_xor(s2, off); }
  float mean = s1 * (1.0f / 256.0f);
  float var = s2 * (1.0f / 256.0f) - mean * mean;
  float rstd = rsqrtf(var + LN_EPS);
  f32x4 gv = *(const f32x4*)(gamma + c0);
  f32x4 bv = *(const f32x4*)(beta + c0);
  ushort4 o;
  o.x = (unsigned short)f2bf((v[0] - mean) * rstd * gv[0] + bv[0]);
  o.y = (unsigned short)f2bf((v[1] - mean) * rstd * gv[1] + bv[1]);
  o.z = (unsigned short)f2bf((v[2] - mean) * rstd * gv[2] + bv[2]);
  o.w = (unsigned short)f2bf((v[3] - mean) * rstd * gv[3] + bv[3]);
  short* dst = which ? tok_prev : tok_cur;
  *(ushort4*)(dst + ((size_t)bt * 1024 + n) * 256 + c0) = o;
}

// -------- pass 1: denominators; LDS-staged k shared by all 4 waves -------------
// block = (64 n-rows, 1 head, 1 bt); sweeps 1024 m in 8 rounds of 128 (8 subtiles)
__global__ __launch_bounds__(256) void denom_kernel(const short* __restrict__ q,
  const short* __restrict__ k, float* __restrict__ dinv)
{
  __shared__ short kst[2][4096];   // [buf][slot(8)][row(16)][d(32)] = 8 KB each
  const int tid = threadIdx.x, wid = tid >> 6, lane = tid & 63;
  const int quad = lane >> 4, l15 = lane & 15;
  const int h = blockIdx.y, bt = blockIdx.z;
  const int n0 = blockIdx.x * 64 + wid * 16;
  const size_t base = ((size_t)bt * 8 + h) * 1024 * 32;
  bf16x8 qf = *(const bf16x8*)(q + base + (size_t)(n0 + l15) * 32 + quad * 8);
  // staging: wave w loads slots w and w+4 (each slot = 16 m-rows = 1 KB, contiguous)
  const short* ksA = k + base + (size_t)(wid * 16) * 32 + lane * 8;
  const short* ksB = k + base + (size_t)((wid + 4) * 16) * 32 + lane * 8;
  short* lwA = &kst[0][wid * 512 + lane * 8];
  short* lwB = &kst[0][(wid + 4) * 512 + lane * 8];

  f32x4 z = {0.f, 0.f, 0.f, 0.f};
  float sum0 = 0, sum1 = 0, sum2 = 0, sum3 = 0;

  bf16x8 stA = *(const bf16x8*)ksA;
  bf16x8 stB = *(const bf16x8*)ksB;

  #pragma unroll 1
  for (int rd = 0; rd < 8; ++rd) {
    const int buf = rd & 1;
    *(bf16x8*)(lwA + buf * 4096) = stA;
    *(bf16x8*)(lwB + buf * 4096) = stB;
    __syncthreads();
    if (rd < 7) {
      stA = *(const bf16x8*)(ksA + (size_t)(rd + 1) * 128 * 32);
      stB = *(const bf16x8*)(ksB + (size_t)(rd + 1) * 128 * 32);
    }
    #pragma unroll
    for (int s = 0; s < 8; ++s) {
      bf16x8 kf = *(const bf16x8*)&kst[buf][s * 512 + l15 * 32 + quad * 8];
      f32x4 sc = __builtin_amdgcn_mfma_f32_16x16x32_bf16(qf, kf, z, 0, 0, 0);
      sum0 += fast_exp2(sc[0]); sum1 += fast_exp2(sc[1]);
      sum2 += fast_exp2(sc[2]); sum3 += fast_exp2(sc[3]);
    }
    __syncthreads();
  }
  #pragma unroll
  for (int off = 1; off < 16; off <<= 1) {
    sum0 += __shfl_xor(sum0, off); sum1 += __shfl_xor(sum1, off);
    sum2 += __shfl_xor(sum2, off); sum3 += __shfl_xor(sum3, off);
  }
  if (l15 == 0) {
    float* dp = dinv + ((size_t)bt * 8 + h) * 1024 + n0 + quad * 4;
    dp[0] = 1.f / sum0; dp[1] = 1.f / sum1; dp[2] = 1.f / sum2; dp[3] = 1.f / sum3;
  }
}

// -------- pass 2: probabilities; LDS-staged k (all 8 heads per m-tile) ---------
// grid: (16 n-strips, 8 m-chunks, 22 bt); m-chunk = 128 = 8 m-tiles of 16
__global__ __launch_bounds__(256) void prob_kernel(const short* __restrict__ q,
  const short* __restrict__ k, const float* __restrict__ dinv, float* __restrict__ out)
{
  __shared__ short kst[2][4096];   // [buf][head(8)][row(16)][d(32)] = 8 KB each
  const int tid = threadIdx.x, wid = tid >> 6, lane = tid & 63;
  const int quad = lane >> 4, l15 = lane & 15;
  const int bt = blockIdx.z;
  const int n0 = blockIdx.x * 64 + wid * 16;
  const int mbase = blockIdx.y * 128;
  const int b = bt / 11, t = bt - b * 11;
  bf16x8 qf[8];
  float invd[8][4];
  #pragma unroll
  for (int h = 0; h < 8; ++h) {
    const size_t base = ((size_t)bt * 8 + h) * 1024 * 32;
    qf[h] = *(const bf16x8*)(q + base + (size_t)(n0 + l15) * 32 + quad * 8);
    const float* dp = dinv + ((size_t)bt * 8 + h) * 1024 + n0 + quad * 4;
    #pragma unroll
    for (int r = 0; r < 4; ++r) invd[h][r] = dp[r] * 0.125f;
  }
  // staging: wave w loads heads w and w+4 for the current m-tile (1 KB each)
  const short* ksA = k + (((size_t)bt * 8 + wid    ) * 1024 + mbase) * 32 + lane * 8;
  const short* ksB = k + (((size_t)bt * 8 + wid + 4) * 1024 + mbase) * 32 + lane * 8;
  short* lwA = &kst[0][wid * 512 + lane * 8];
  short* lwB = &kst[0][(wid + 4) * 512 + lane * 8];

  float* ob = out + ((size_t)(b * 12 + t + 1)) * 1024 * 1024
                  + (size_t)(n0 + quad * 4) * 1024 + l15;
  f32x4 z = {0.f, 0.f, 0.f, 0.f};

  bf16x8 stA = *(const bf16x8*)ksA;
  bf16x8 stB = *(const bf16x8*)ksB;

  #pragma unroll 1
  for (int mt = 0; mt < 8; ++mt) {
    const int buf = mt & 1;
    *(bf16x8*)(lwA + buf * 4096) = stA;
    *(bf16x8*)(lwB + buf * 4096) = stB;
    __syncthreads();
    if (mt < 7) {
      stA = *(const bf16x8*)(ksA + (size_t)(mt + 1) * 16 * 32);
      stB = *(const bf16x8*)(ksB + (size_t)(mt + 1) * 16 * 32);
    }
    float P0 = 0, P1 = 0, P2 = 0, P3 = 0;
    #pragma unroll
    for (int h = 0; h < 8; ++h) {
      bf16x8 kf = *(const bf16x8*)&kst[buf][h * 512 + l15 * 32 + quad * 8];
      f32x4 s = __builtin_amdgcn_mfma_f32_16x16x32_bf16(qf[h], kf, z, 0, 0, 0);
      P0 += fast_exp2(s[0]) * invd[h][0];
      P1 += fast_exp2(s[1]) * invd[h][1];
      P2 += fast_exp2(s[2]) * invd[h][2];
      P3 += fast_exp2(s[3]) * invd[h][3];
    }
    float* op = ob + mbase + mt * 16;
    op[0] = P0; op[1024] = P1; op[2048] = P2; op[3072] = P3;
    __syncthreads();
  }
}

// -------------- identity slab at t=0 -------------------------------------------
__global__ __launch_bounds__(256) void eye_kernel(float* __restrict__ out) {
  int gid = blockIdx.x * 256 + threadIdx.x;
  int b = gid >> 18, rem = gid & 262143;
  int n = rem >> 8, m4 = rem & 255;
  f32x4 v = {0.f, 0.f, 0.f, 0.f};
  int c = n - m4 * 4;
  if (c >= 0 && c < 4) v[c] = 1.0f;
  *(f32x4*)(out + (size_t)b * 12582912 + (size_t)n * 1024 + m4 * 4) = v;
}

extern "C" void kernel_launch(void* const* d_in, const int* in_sizes, int n_in,
                              void* d_out, int out_size, void* d_ws, size_t ws_size,
                              hipStream_t stream)
{
  const float* sf   = (const float*)d_in[0];
  const float* sa   = (const float*)d_in[1];
  const float* te   = (const float*)d_in[2];
  const float* Wf   = (const float*)d_in[3];
  const float* bfv  = (const float*)d_in[4];
  const float* Wa   = (const float*)d_in[5];
  const float* ba   = (const float*)d_in[6];
  const float* Win  = (const float*)d_in[7];
  const float* binv = (const float*)d_in[8];
  const float* gam  = (const float*)d_in[9];
  const float* bet  = (const float*)d_in[10];
  float* out = (float*)d_out;

  char* w = (char*)d_ws;
  short* featproj = (short*)w;  w += 12582912;
  short* tok_cur  = (short*)w;  w += 11534336;
  short* tok_prev = (short*)w;  w += 11534336;
  short* qb       = (short*)w;  w += 11534336;
  short* kb       = (short*)w;  w += 11534336;
  float* dinv     = (float*)w;  w += 720896;

  gemm_feat<<<dim3(384, 4), 256, 0, stream>>>(sf, Wf, bfv, featproj);
  anchor_ln<<<dim3(11264), 256, 0, stream>>>(featproj, sa, te, Wa, ba, gam, bet, tok_cur, tok_prev);
  gemm_qk<<<dim3(352, 4, 2), 256, 0, stream>>>(tok_cur, tok_prev, Win, binv, qb, kb);
  denom_kernel<<<dim3(16, 8, 22), 256, 0, stream>>>(qb, kb, dinv);
  prob_kernel<<<dim3(16, 8, 22), 256, 0, stream>>>(qb, kb, dinv, out);
  eye_kernel<<<dim3(2048), 256, 0, stream>>>(out);
}